// Round 1
// 806.764 us; speedup vs baseline: 1.0080x; 1.0080x over previous
//
#include <hip/hip_runtime.h>
#include <cstdint>
#include <cmath>

// Problem constants: N=131072, M=64, K=8.
#define N_TOT 131072
#define NBLK  1024               // blocks in main kernel
#define WPB   4                  // waves per block (256 threads)
#define ITERS (N_TOT / (NBLK * WPB))   // 32 n per wave, exact

typedef double f64x4 __attribute__((ext_vector_type(4)));

// Async global->LDS, 16B per lane. LDS dest = wave-uniform base + lane*16B,
// global src is per-lane (guide §5 / m97 / m104).
__device__ __forceinline__ void gld_lds16(const float* g, float* l) {
  __builtin_amdgcn_global_load_lds(
      (const __attribute__((address_space(1))) void*)g,
      (__attribute__((address_space(3))) void*)l, 16, 0, 0);
}

// One wave per n.  Per n: stage the 4 arrays (2048 floats) linearly into
// wave-private LDS via global_load_lds, then compute the 16x16 f64 MFMA
// C = [Hr|Hi]^T [Vr|Vi] over m=0..63 (sixteen 16x16x4 f64 MFMAs, two
// accumulator chains).  C blocks give re/im of h_k^T v_l; epilogue combines
// blocks via shfl_xor(8/32/40), row-sums over l via shfl_xor(1/2/4), and the
// 8 diagonal lanes accumulate log2(1 + nom/denom).
//
// MFMA f64 16x16x4 fragment layout (classic CDNA mapping, same family as the
// m89-verified f32 16x16 layout): A[r][k] at lane k*16+r, B[k][c] at lane
// k*16+c, C[r][c]: lane holds r=(lane>>4)*4+v, c=lane&15.
__global__ __launch_bounds__(256, 4)
void srl_main(const float* __restrict__ Hr, const float* __restrict__ Hi,
              const float* __restrict__ Vr, const float* __restrict__ Vi,
              const float* __restrict__ noise_p, float* __restrict__ partials) {
  __shared__ float buf[WPB][2048];   // 32 KB: wave-private [Hr|Hi|Vr|Vi] x 512
  __shared__ float red[WPB];

  const int tid  = threadIdx.x;
  const int w    = tid >> 6;
  const int lane = tid & 63;
  const int c    = lane & 15;      // A-row r / B-col index
  const int hi   = lane >> 4;      // K-subindex within one mfma (0..3)
  const int c7   = c & 7;          // column within Hr-or-Hi (Vr-or-Vi)
  const int sel  = c >> 3;         // 0: real array, 1: imag array
  const float noise = noise_p[0];

  float* base = buf[w];
  // Lane-fixed LDS word base: A element for mfma t lives at rbase + 32*t
  // (m = 4t + hi, word = sel*512 + m*8 + c7).  B is the same +1024 (V arrays).
  const int rbase = sel * 512 + hi * 8 + c7;

  float acc = 0.f;
  const int n0 = blockIdx.x * (ITERS * WPB) + w;

  for (int it = 0; it < ITERS; ++it) {
    const size_t gbase = (size_t)(n0 + it * WPB) * 512 + (size_t)(lane * 4);

    // Drain previous iteration's LDS reads before overwriting the buffer.
    asm volatile("s_waitcnt lgkmcnt(0)" ::: "memory");
    gld_lds16(Hr + gbase,       base);
    gld_lds16(Hr + gbase + 256, base + 256);
    gld_lds16(Hi + gbase,       base + 512);
    gld_lds16(Hi + gbase + 256, base + 768);
    gld_lds16(Vr + gbase,       base + 1024);
    gld_lds16(Vr + gbase + 256, base + 1280);
    gld_lds16(Vi + gbase,       base + 1536);
    gld_lds16(Vi + gbase + 256, base + 1792);
    asm volatile("s_waitcnt vmcnt(0)" ::: "memory");

    // Sixteen f64 MFMAs over m; split into two chains to halve dep latency.
    f64x4 a0 = {0., 0., 0., 0.}, a1 = {0., 0., 0., 0.};
#pragma unroll
    for (int t = 0; t < 16; t += 2) {
      const double xa0 = (double)base[rbase + 32 * t];
      const double xb0 = (double)base[1024 + rbase + 32 * t];
      const double xa1 = (double)base[rbase + 32 * (t + 1)];
      const double xb1 = (double)base[1024 + rbase + 32 * (t + 1)];
      a0 = __builtin_amdgcn_mfma_f64_16x16x4f64(xa0, xb0, a0, 0, 0, 0);
      a1 = __builtin_amdgcn_mfma_f64_16x16x4f64(xa1, xb1, a1, 0, 0, 0);
    }

    // Epilogue: lane holds C[r][cl], r = 4*hi + v, cl = c.
    //   real[r][cl] = C[r][cl] - C[r+8][cl+8]   (partner = lane ^ 40)
    //   imag[r][cl] = C[r][cl+8] + C[r+8][cl]   (lane ^ 8, lane ^ 32)
    float nrm[4], nomv[4];
#pragma unroll
    for (int v = 0; v < 4; ++v) {
      const float cf  = (float)(a0[v] + a1[v]);
      const float x8  = __shfl_xor(cf, 8);
      const float x32 = __shfl_xor(cf, 32);
      const float x40 = __shfl_xor(cf, 40);
      const float re  = cf - x40;
      const float im  = x8 + x32;
      nrm[v]  = fmaf(re, re, im * im);   // |h_{k=r}^T v_{l=cl}|^2
      nomv[v] = nrm[v];                  // diagonal candidate (pre row-sum)
    }
    // Row sum over l (the 8-col octet; cl and cl+8 never mix under xor<8).
#pragma unroll
    for (int v = 0; v < 4; ++v) {
      nrm[v] += __shfl_xor(nrm[v], 1);
      nrm[v] += __shfl_xor(nrm[v], 2);
      nrm[v] += __shfl_xor(nrm[v], 4);
    }
    // Diagonal lanes (r == cl, r < 8): hi<2 and c>>2 == hi, with v = c&3.
    if (hi < 2 && (c >> 2) == hi) {
      const int   v     = c & 3;
      const float nom   = nomv[v];
      const float denom = (nrm[v] - nom) + noise;
      acc += log2f(1.f + nom / denom);
    }
  }

  // Wave reduce (only the 8 diag lanes are nonzero), then block reduce.
#pragma unroll
  for (int off = 1; off < 64; off <<= 1) acc += __shfl_xor(acc, off);
  if (lane == 0) red[w] = acc;
  __syncthreads();
  if (tid == 0) partials[blockIdx.x] = red[0] + red[1] + red[2] + red[3];
}

__global__ __launch_bounds__(256)
void srl_finalize(const float* __restrict__ partials, float* __restrict__ out) {
  const int tid = threadIdx.x;
  float a = 0.f;
#pragma unroll
  for (int i = 0; i < NBLK / 256; ++i) a += partials[tid + i * 256];
#pragma unroll
  for (int off = 1; off < 64; off <<= 1) a += __shfl_xor(a, off);
  __shared__ float r[4];
  if ((tid & 63) == 0) r[tid >> 6] = a;
  __syncthreads();
  if (tid == 0) out[0] = -(r[0] + r[1] + r[2] + r[3]) * (1.f / (float)N_TOT);
}

extern "C" void kernel_launch(void* const* d_in, const int* in_sizes, int n_in,
                              void* d_out, int out_size, void* d_ws, size_t ws_size,
                              hipStream_t stream) {
  const float* Hr = (const float*)d_in[0];
  const float* Hi = (const float*)d_in[1];
  const float* Vr = (const float*)d_in[2];
  const float* Vi = (const float*)d_in[3];
  const float* nz = (const float*)d_in[4];
  float* out      = (float*)d_out;
  float* partials = (float*)d_ws;   // NBLK floats of scratch

  srl_main<<<NBLK, 256, 0, stream>>>(Hr, Hi, Vr, Vi, nz, partials);
  srl_finalize<<<1, 256, 0, stream>>>(partials, out);
}